// Round 19
// baseline (244.810 us; speedup 1.0000x reference)
//
#include <hip/hip_runtime.h>
#include <math.h>

#define BATCH 524288
#define VEC 512
#define NBLK 1024           // co-resident: 4 blocks/CU on 256 CUs
#define SLAB 2048           // rows written by the whole grid per iteration (4 MB)
#define NIT (BATCH / SLAB)  // 256 iterations

static_assert(NBLK * 2 == SLAB, "2 rows per block per iteration");

typedef float f32x4 __attribute__((ext_vector_type(4)));

// Accurate sincos of an f32 phase value: f64 reduction by pi/2 of the exact
// f32 input, then f32 minimax kernels on [-pi/4, pi/4] (~1e-7 abs error).
// Correctness-proven in round 10 (absmax 3.9e-3). DO NOT change.
__device__ __forceinline__ void sincos_acc(float phf, float& s, float& c) {
    const double two_over_pi = 0.6366197723675814;
    const double pio2        = 1.5707963267948966;
    const double ph  = (double)phf;                 // exact
    const double nd  = rint(ph * two_over_pi);      // |nd| <= ~3.4e4, exact int
    const double red = fma(-nd, pio2, ph);          // |red| <= pi/4, err ~1e-12
    const int    q   = ((int)nd) & 3;               // correct for negative nd
    const float  r   = (float)red;
    const float  r2  = r * r;
    float sp = fmaf(r2, 2.7183114939898219e-6f, -1.9839334836096632e-4f);
    sp = fmaf(r2, sp, 8.3333293858894632e-3f);
    sp = fmaf(r2, sp, -1.6666666641626524e-1f);
    sp = r * fmaf(r2, sp, 1.0f);
    float cp = fmaf(r2, 2.4390448796277409e-5f, -1.3886763774609929e-3f);
    cp = fmaf(r2, cp, 4.1666623323739063e-2f);
    cp = fmaf(r2, cp, -4.9999999725103100e-1f);
    cp = fmaf(r2, cp, 1.0f);
    const bool swp = (q & 1);
    float ss = swp ? cp : sp;
    float cc = swp ? sp : cp;
    s = (q & 2)       ? -ss : ss;
    c = ((q + 1) & 2) ? -cc : cc;
}

// Prologue: 256-entry frequency table in d_ws (bit-identical to R10's chain).
// FREQUENCY CHAIN -- correctness-critical: e = (i * fl32(1/255)) * 4 (arcp
// reciprocal form), f = CR f64 pow. DO NOT change.
__global__ void freq_table_kernel(float* __restrict__ fw) {
    const int i = threadIdx.x;                  // 0..255
    const float RCP255 = 1.0f / 255.0f;
    const float e = ((float)i * RCP255) * 4.0f;
    fw[i] = (float)pow(10.0, (double)e);
}

// A/B vs R13/R16/R17 (single variable = write-front topology):
// CO-RESIDENT grid + GLOBALLY SWEEPING front -- fill's exact configuration.
// R16's sweep failed at 8x oversubscription (retirement skew -> scatter);
// 1024 blocks are fully resident so the front stays coherent.
__global__ __launch_bounds__(256, 4) void input_layer_kernel(
        const float* __restrict__ x, const float* __restrict__ fw,
        float* __restrict__ out) {
    __shared__ float xs[2 * NIT];               // 512 x-values: rows k*2048+2b+{0,1}
    const int tid = threadIdx.x;
    const int b   = blockIdx.x;

    // One-time strided gather (512 x 4 B). Hot loop: ZERO global reads.
    if (tid < 256) {
        xs[2 * tid]     = x[(size_t)tid * SLAB + 2 * b];
        xs[2 * tid + 1] = x[(size_t)tid * SLAB + 2 * b + 1];
    }

    const int   q  = tid & 127;                 // float4 index within row
    const float f0 = fw[2 * q];                 // table freqs (L2-resident)
    const float f1 = fw[2 * q + 1];

    __syncthreads();

    const int half = tid >> 7;                  // 0 or 1: which of the block's 2 rows
    for (int k = 0; k < NIT; ++k) {
        const float xv = xs[2 * k + half];      // wave-uniform -> LDS broadcast
        float s0, c0, s1, c1;
        sincos_acc(xv * f0, s0, c0);            // phase rounded to f32, like the ref
        sincos_acc(xv * f1, s1, c1);
        f32x4 o = {s0, c0, s1, c1};
        const size_t row = (size_t)k * SLAB + 2 * b + half;
        f32x4* dst = reinterpret_cast<f32x4*>(out + row * VEC) + q;
        *dst = o;                               // cached store (R13 A/B winner)
    }
}

extern "C" void kernel_launch(void* const* d_in, const int* in_sizes, int n_in,
                              void* d_out, int out_size, void* d_ws, size_t ws_size,
                              hipStream_t stream) {
    const float* x = (const float*)d_in[0];
    float* out = (float*)d_out;
    float* fw  = (float*)d_ws;                  // 1 KB frequency table
    freq_table_kernel<<<1, 256, 0, stream>>>(fw);
    input_layer_kernel<<<NBLK, 256, 0, stream>>>(x, fw, out);
}